// Round 11
// baseline (151.198 us; speedup 1.0000x reference)
//
#include <hip/hip_runtime.h>

#define BB    32
#define CINc  64
#define HHc   32
#define WWc   32
#define COc   64
#define KSc   7
#define GGc   8
#define PADc  3
#define CPGc  8
#define NPIX  (HHc * WWc)      // 1024
#define TILEH 8
#define HALOH (TILEH + 6)      // 14
#define HALOW (WWc + 6)        // 38
#define NPOS  (HALOH * HALOW)  // 532

typedef _Float16 half2v __attribute__((ext_vector_type(2)));

#if defined(__has_builtin)
#if __has_builtin(__builtin_amdgcn_fdot2)
#define HAVE_FDOT2 1
#endif
#endif

// Round 11: software-pipelined staging (xv0/xv1 double buffer, 16 loads in
// flight) + launch_bounds(256,4): grid is 4 blocks/CU anyway, so trade the
// unused 6-wave occupancy for a 128-VGPR budget (round 10's 40 VGPR left the
// load pipeline starved). Everything else identical to round 10.
__global__ __launch_bounds__(256, 4) void fused_kernel(
    const float* __restrict__ x,      // [B][64][32][32]
    const float* __restrict__ wq,     // [64][64]
    const float* __restrict__ wk,
    const float* __restrict__ wv,
    const float* __restrict__ rel_h,  // [32][7]
    const float* __restrict__ rel_w,  // [32][7]
    const float* __restrict__ cv,     // [8]
    float* __restrict__ out)          // [B][64][32][32]
{
    __shared__ __attribute__((aligned(16))) float4 kpl[NPOS];   // k[0:8] as 4x half2
    __shared__ __attribute__((aligned(16))) float4 vpl0[NPOS];  // v[0:4] f32
    __shared__ __attribute__((aligned(16))) float4 vpl1[NPOS];  // v[4:8] f32

    // XCD swizzle: all 32 blocks of image b satisfy blockIdx ≡ const (mod 8)
    const int bi   = blockIdx.x;
    const int xcd  = bi & 7;
    const int sIdx = bi >> 3;            // 0..127
    const int im   = sIdx >> 5;          // 0..3 image-within-XCD
    const int j    = sIdx & 31;          // 32 blocks per image
    const int b    = im * 8 + xcd;
    const int g    = j >> 2;
    const int tile = j & 3;
    const int o0   = g * CPGc;
    const int tid  = threadIdx.x;

    const int y0  = tile * TILEH - PADc;             // first halo row (global y)
    const int yv0 = (y0 < 0) ? 0 : y0;               // first valid global y
    const int yv1 = (y0 + HALOH - 1 > HHc - 1) ? (HHc - 1) : (y0 + HALOH - 1);
    const int nvp = ((yv1 - yv0) + 1) << 5;          // valid positions (rows*32)
    const int r0  = yv0 - y0;                        // halo row of first valid row
    const float* xb = x + (size_t)b * CINc * NPIX;

    // ---------- zero-fill all positions (staging overwrites valid ones) ----------
    {
        const float4 z = {0.f, 0.f, 0.f, 0.f};
        for (int p = tid; p < NPOS; p += 256) {
            kpl[p] = z; vpl0[p] = z; vpl1[p] = z;
        }
    }
    __syncthreads();

    // ---------- stage k,v: 2-deep software-pipelined over c0 chunks ----------
#pragma unroll 1
    for (int i = tid; i < nvp; i += 256) {
        const int row = i >> 5;
        const int xx  = i & 31;
        const int y   = yv0 + row;
        const float* xp = xb + y * WWc + xx;

        float ak[CPGc], av[CPGc];
#pragma unroll
        for (int oi = 0; oi < CPGc; ++oi) { ak[oi] = 0.f; av[oi] = 0.f; }

        float xv0[8], xv1[8];
#pragma unroll
        for (int jj = 0; jj < 8; ++jj)
            xv0[jj] = xp[jj * NPIX];                 // chunk 0

#pragma unroll
        for (int c0 = 0; c0 < CINc; c0 += 16) {
            // prefetch chunk c0+8 while computing chunk c0
#pragma unroll
            for (int jj = 0; jj < 8; ++jj)
                xv1[jj] = xp[(c0 + 8 + jj) * NPIX];
#pragma unroll
            for (int oi = 0; oi < CPGc; ++oi) {
                const float* wkr = wk + (o0 + oi) * CINc + c0;  // uniform -> s_load
                const float* wvr = wv + (o0 + oi) * CINc + c0;
#pragma unroll
                for (int jj = 0; jj < 8; ++jj) {
                    ak[oi] = fmaf(xv0[jj], wkr[jj], ak[oi]);
                    av[oi] = fmaf(xv0[jj], wvr[jj], av[oi]);
                }
            }
            // prefetch chunk c0+16 while computing chunk c0+8
            if (c0 + 16 < CINc) {
#pragma unroll
                for (int jj = 0; jj < 8; ++jj)
                    xv0[jj] = xp[(c0 + 16 + jj) * NPIX];
            }
#pragma unroll
            for (int oi = 0; oi < CPGc; ++oi) {
                const float* wkr = wk + (o0 + oi) * CINc + c0 + 8;
                const float* wvr = wv + (o0 + oi) * CINc + c0 + 8;
#pragma unroll
                for (int jj = 0; jj < 8; ++jj) {
                    ak[oi] = fmaf(xv1[jj], wkr[jj], ak[oi]);
                    av[oi] = fmaf(xv1[jj], wvr[jj], av[oi]);
                }
            }
        }

        const int p = (r0 + row) * HALOW + (xx + PADc);
        float4 kst;
        half2v* kp = (half2v*)&kst;
#pragma unroll
        for (int jj = 0; jj < 4; ++jj)
            kp[jj] = half2v{(_Float16)ak[2 * jj], (_Float16)ak[2 * jj + 1]};
        kpl[p]  = kst;
        vpl0[p] = (float4){av[0], av[1], av[2], av[3]};
        vpl1[p] = (float4){av[4], av[5], av[6], av[7]};
    }

    // ---------- q for own pixel (same 2-deep pipeline) ----------
    const int w  = tid & 31;
    const int lh = tid >> 5;               // 0..7
    const int h  = tile * TILEH + lh;
    const int poff = h * WWc + w;

    float q[CPGc];
#pragma unroll
    for (int oi = 0; oi < CPGc; ++oi) q[oi] = 0.f;

    {
        const float* xp = xb + poff;
        float xv0[8], xv1[8];
#pragma unroll
        for (int jj = 0; jj < 8; ++jj)
            xv0[jj] = xp[jj * NPIX];
#pragma unroll
        for (int c0 = 0; c0 < CINc; c0 += 16) {
#pragma unroll
            for (int jj = 0; jj < 8; ++jj)
                xv1[jj] = xp[(c0 + 8 + jj) * NPIX];
#pragma unroll
            for (int oi = 0; oi < CPGc; ++oi) {
                const float* wqr = wq + (o0 + oi) * CINc + c0;  // uniform -> s_load
#pragma unroll
                for (int jj = 0; jj < 8; ++jj)
                    q[oi] = fmaf(xv0[jj], wqr[jj], q[oi]);
            }
            if (c0 + 16 < CINc) {
#pragma unroll
                for (int jj = 0; jj < 8; ++jj)
                    xv0[jj] = xp[(c0 + 16 + jj) * NPIX];
            }
#pragma unroll
            for (int oi = 0; oi < CPGc; ++oi) {
                const float* wqr = wq + (o0 + oi) * CINc + c0 + 8;
#pragma unroll
                for (int jj = 0; jj < 8; ++jj)
                    q[oi] = fmaf(xv1[jj], wqr[jj], q[oi]);
            }
        }
    }

#if HAVE_FDOT2
    half2v q2[4];
#pragma unroll
    for (int jj = 0; jj < 4; ++jj)
        q2[jj] = half2v{(_Float16)q[2 * jj], (_Float16)q[2 * jj + 1]};
#endif

    // qrel[t] = sum_oi q[oi] * rel[oi][t]
    const bool use_h = (g < 4);
    const float* relp = use_h ? (rel_h + o0 * KSc) : (rel_w + (o0 - 32) * KSc);
    float qrel[KSc];
#pragma unroll
    for (int tt = 0; tt < KSc; ++tt) {
        float s = 0.f;
#pragma unroll
        for (int oi = 0; oi < CPGc; ++oi)
            s = fmaf(q[oi], relp[oi * KSc + tt], s);
        qrel[tt] = s;
    }

    __syncthreads();

    // ---------- taps: score -> exp -> den & acc, fully fused per tap ----------
    float den = 0.f;
    float acc[CPGc];
#pragma unroll
    for (int oi = 0; oi < CPGc; ++oi) acc[oi] = 0.f;

#pragma unroll
    for (int ki = 0; ki < KSc; ++ki) {
        const int rbase = (lh + ki) * HALOW + w;
#pragma unroll
        for (int kj = 0; kj < KSc; ++kj) {
            const int p = rbase + kj;
            const float4 kraw = kpl[p];
            const float4 v0   = vpl0[p];
            const float4 v1   = vpl1[p];

            float s = use_h ? qrel[ki] : qrel[kj];
#if HAVE_FDOT2
            const half2v* kh = (const half2v*)&kraw;
            s = __builtin_amdgcn_fdot2(q2[0], kh[0], s, false);
            s = __builtin_amdgcn_fdot2(q2[1], kh[1], s, false);
            s = __builtin_amdgcn_fdot2(q2[2], kh[2], s, false);
            s = __builtin_amdgcn_fdot2(q2[3], kh[3], s, false);
#else
            const half2v* kh = (const half2v*)&kraw;
#pragma unroll
            for (int jj = 0; jj < 4; ++jj) {
                s = fmaf(q[2 * jj],     (float)kh[jj].x, s);
                s = fmaf(q[2 * jj + 1], (float)kh[jj].y, s);
            }
#endif
            const float e = __expf(s);   // |s| stat-bounded << 88: no-max softmax
            den += e;
            acc[0] = fmaf(e, v0.x, acc[0]); acc[1] = fmaf(e, v0.y, acc[1]);
            acc[2] = fmaf(e, v0.z, acc[2]); acc[3] = fmaf(e, v0.w, acc[3]);
            acc[4] = fmaf(e, v1.x, acc[4]); acc[5] = fmaf(e, v1.y, acc[5]);
            acc[6] = fmaf(e, v1.z, acc[6]); acc[7] = fmaf(e, v1.w, acc[7]);
        }
    }

    // ---------- adaptive mask + write ----------
    const int  r  = min(h, HHc - 1 - h);
    const int  lo = (h <= HHc - 1 - h) ? r : r + 1;
    const int  hi = HHc - 1 - r;
    const bool in_ring = (w >= lo) && (w <= hi);
    const float cvg = cv[g];
    float om = ((float)r - 15.0f + cvg * 16.0f) * (1.0f / 3.0f) + 1.0f;
    om = fminf(fmaxf(om, 0.0f), 1.0f);
    const float maskv = in_ring ? om : 1.0f;
    const float scale = maskv / den;

    float* ob = out + ((size_t)b * COc + o0) * NPIX + poff;
#pragma unroll
    for (int oi = 0; oi < CPGc; ++oi)
        ob[(size_t)oi * NPIX] = acc[oi] * scale;
}

extern "C" void kernel_launch(void* const* d_in, const int* in_sizes, int n_in,
                              void* d_out, int out_size, void* d_ws, size_t ws_size,
                              hipStream_t stream) {
    const float* x     = (const float*)d_in[0];
    const float* wq    = (const float*)d_in[1];
    const float* wk    = (const float*)d_in[2];
    const float* wv    = (const float*)d_in[3];
    const float* rel_h = (const float*)d_in[4];
    const float* rel_w = (const float*)d_in[5];
    const float* cv    = (const float*)d_in[6];
    float* out = (float*)d_out;

    fused_kernel<<<1024, 256, 0, stream>>>(x, wq, wk, wv, rel_h, rel_w, cv, out);
}

// Round 12
// 103.686 us; speedup vs baseline: 1.4582x; 1.4582x over previous
//
#include <hip/hip_runtime.h>

#define BB    32
#define CINc  64
#define HHc   32
#define WWc   32
#define COc   64
#define KSc   7
#define GGc   8
#define PADc  3
#define CPGc  8
#define NPIX  (HHc * WWc)      // 1024

typedef _Float16 half2v __attribute__((ext_vector_type(2)));

#if defined(__has_builtin)
#if __has_builtin(__builtin_amdgcn_fdot2)
#define HAVE_FDOT2 1
#endif
#endif

// Full-image blocks: grid 256 = 32 images x 8 groups, 1024 threads = 1 thread
// per pixel. Staging has zero halo overcompute (each thread projects its own
// pixel; k,v,q fused in one x pass). Taps use clamped LDS indices + per-tap
// in-bounds predication instead of physical zero pads (LDS 48 KB). k f16 +
// fdot2; v,e,acc f32 (e unnormalized, can reach e^40 -> f32 mandatory).
// XCD swizzle: all 8 group-blocks of an image share one XCD's L2.
__global__ __launch_bounds__(1024, 4) void fused_kernel(
    const float* __restrict__ x,      // [B][64][32][32]
    const float* __restrict__ wq,     // [64][64]
    const float* __restrict__ wk,
    const float* __restrict__ wv,
    const float* __restrict__ rel_h,  // [32][7]
    const float* __restrict__ rel_w,  // [32][7]
    const float* __restrict__ cv,     // [8]
    float* __restrict__ out)          // [B][64][32][32]
{
    __shared__ __attribute__((aligned(16))) float4 kpl[NPIX];   // k[0:8] as 4x half2
    __shared__ __attribute__((aligned(16))) float4 vpl0[NPIX];  // v[0:4] f32
    __shared__ __attribute__((aligned(16))) float4 vpl1[NPIX];  // v[4:8] f32

    const int bi  = blockIdx.x;
    const int xcd = bi & 7;            // 32 blocks per XCD
    const int t   = bi >> 3;           // 0..31
    const int im  = t & 3;             // image-within-XCD
    const int g   = t >> 2;            // 0..7
    const int b   = im * 8 + xcd;
    const int o0  = g * CPGc;
    const int tid = threadIdx.x;       // = pixel index 0..1023
    const int w   = tid & 31;
    const int h   = tid >> 5;

    const float* xb = x + (size_t)b * CINc * NPIX;
    const float* xp = xb + tid;

    // ---------- fused k,v,q projection for own pixel ----------
    float ak[CPGc], av[CPGc], aq[CPGc];
#pragma unroll
    for (int oi = 0; oi < CPGc; ++oi) { ak[oi] = 0.f; av[oi] = 0.f; aq[oi] = 0.f; }

    for (int c0 = 0; c0 < CINc; c0 += 8) {
        float xv[8];
#pragma unroll
        for (int jj = 0; jj < 8; ++jj)
            xv[jj] = xp[(c0 + jj) * NPIX];
#pragma unroll
        for (int oi = 0; oi < CPGc; ++oi) {
            const float* wkr = wk + (o0 + oi) * CINc + c0;  // uniform -> s_load
            const float* wvr = wv + (o0 + oi) * CINc + c0;
            const float* wqr = wq + (o0 + oi) * CINc + c0;
#pragma unroll
            for (int jj = 0; jj < 8; ++jj) {
                ak[oi] = fmaf(xv[jj], wkr[jj], ak[oi]);
                av[oi] = fmaf(xv[jj], wvr[jj], av[oi]);
                aq[oi] = fmaf(xv[jj], wqr[jj], aq[oi]);
            }
        }
    }

    {
        float4 kst;
        half2v* kp = (half2v*)&kst;
#pragma unroll
        for (int jj = 0; jj < 4; ++jj)
            kp[jj] = half2v{(_Float16)ak[2 * jj], (_Float16)ak[2 * jj + 1]};
        kpl[tid]  = kst;
        vpl0[tid] = (float4){av[0], av[1], av[2], av[3]};
        vpl1[tid] = (float4){av[4], av[5], av[6], av[7]};
    }

#if HAVE_FDOT2
    half2v q2[4];
#pragma unroll
    for (int jj = 0; jj < 4; ++jj)
        q2[jj] = half2v{(_Float16)aq[2 * jj], (_Float16)aq[2 * jj + 1]};
#endif

    // qrel[t] = sum_oi q[oi] * rel[oi][t]
    const bool use_h = (g < 4);
    const float* relp = use_h ? (rel_h + o0 * KSc) : (rel_w + (o0 - 32) * KSc);
    float qrel[KSc];
#pragma unroll
    for (int tt = 0; tt < KSc; ++tt) {
        float s = 0.f;
#pragma unroll
        for (int oi = 0; oi < CPGc; ++oi)
            s = fmaf(aq[oi], relp[oi * KSc + tt], s);
        qrel[tt] = s;
    }

    __syncthreads();

    // per-kj clamped col + in-bounds mask (reused over all ki)
    int  xcl[KSc];
    bool xin[KSc];
#pragma unroll
    for (int kj = 0; kj < KSc; ++kj) {
        const int xx = w + kj - PADc;
        xin[kj] = (xx >= 0) && (xx < WWc);
        xcl[kj] = min(max(xx, 0), WWc - 1);
    }

    // ---------- taps: clamped reads + predication ----------
    float den = 0.f;
    float acc[CPGc];
#pragma unroll
    for (int oi = 0; oi < CPGc; ++oi) acc[oi] = 0.f;

#pragma unroll
    for (int ki = 0; ki < KSc; ++ki) {
        const int y   = h + ki - PADc;
        const bool yin = (y >= 0) && (y < HHc);
        const int base = min(max(y, 0), HHc - 1) * WWc;
#pragma unroll
        for (int kj = 0; kj < KSc; ++kj) {
            const int p = base + xcl[kj];
            const float4 kraw = kpl[p];
            const float4 v0   = vpl0[p];
            const float4 v1   = vpl1[p];
            const bool in = yin && xin[kj];

            float d = 0.f;
#if HAVE_FDOT2
            const half2v* kh = (const half2v*)&kraw;
            d = __builtin_amdgcn_fdot2(q2[0], kh[0], d, false);
            d = __builtin_amdgcn_fdot2(q2[1], kh[1], d, false);
            d = __builtin_amdgcn_fdot2(q2[2], kh[2], d, false);
            d = __builtin_amdgcn_fdot2(q2[3], kh[3], d, false);
#else
            const half2v* kh = (const half2v*)&kraw;
#pragma unroll
            for (int jj = 0; jj < 4; ++jj) {
                d = fmaf(aq[2 * jj],     (float)kh[jj].x, d);
                d = fmaf(aq[2 * jj + 1], (float)kh[jj].y, d);
            }
#endif
            const float s = (use_h ? qrel[ki] : qrel[kj]) + (in ? d : 0.f);
            const float e = __expf(s);      // OOB: e = exp(qrel) exactly (ref zero-pad)
            den += e;
            const float ev = in ? e : 0.f;  // OOB taps contribute no v
            acc[0] = fmaf(ev, v0.x, acc[0]); acc[1] = fmaf(ev, v0.y, acc[1]);
            acc[2] = fmaf(ev, v0.z, acc[2]); acc[3] = fmaf(ev, v0.w, acc[3]);
            acc[4] = fmaf(ev, v1.x, acc[4]); acc[5] = fmaf(ev, v1.y, acc[5]);
            acc[6] = fmaf(ev, v1.z, acc[6]); acc[7] = fmaf(ev, v1.w, acc[7]);
        }
    }

    // ---------- adaptive mask + write ----------
    const int  r  = min(h, HHc - 1 - h);
    const int  lo = (h <= HHc - 1 - h) ? r : r + 1;
    const int  hi = HHc - 1 - r;
    const bool in_ring = (w >= lo) && (w <= hi);
    const float cvg = cv[g];
    float om = ((float)r - 15.0f + cvg * 16.0f) * (1.0f / 3.0f) + 1.0f;
    om = fminf(fmaxf(om, 0.0f), 1.0f);
    const float maskv = in_ring ? om : 1.0f;
    const float scale = maskv / den;

    float* ob = out + ((size_t)b * COc + o0) * NPIX + tid;
#pragma unroll
    for (int oi = 0; oi < CPGc; ++oi)
        ob[(size_t)oi * NPIX] = acc[oi] * scale;
}

extern "C" void kernel_launch(void* const* d_in, const int* in_sizes, int n_in,
                              void* d_out, int out_size, void* d_ws, size_t ws_size,
                              hipStream_t stream) {
    const float* x     = (const float*)d_in[0];
    const float* wq    = (const float*)d_in[1];
    const float* wk    = (const float*)d_in[2];
    const float* wv    = (const float*)d_in[3];
    const float* rel_h = (const float*)d_in[4];
    const float* rel_w = (const float*)d_in[5];
    const float* cv    = (const float*)d_in[6];
    float* out = (float*)d_out;

    fused_kernel<<<256, 1024, 0, stream>>>(x, wq, wk, wv, rel_h, rel_w, cv, out);
}

// Round 13
// 87.525 us; speedup vs baseline: 1.7275x; 1.1846x over previous
//
#include <hip/hip_runtime.h>

#define BB    32
#define CINc  64
#define HHc   32
#define WWc   32
#define COc   64
#define KSc   7
#define GGc   8
#define PADc  3
#define CPGc  8
#define NPIX  (HHc * WWc)      // 1024

typedef _Float16 h8    __attribute__((ext_vector_type(8)));
typedef _Float16 h2    __attribute__((ext_vector_type(2)));
typedef float    f32x4 __attribute__((ext_vector_type(4)));

#if defined(__has_builtin)
#if __has_builtin(__builtin_amdgcn_fdot2)
#define HAVE_FDOT2 1
#endif
#endif

// MFMA projection: per block (image, group), the q/k/v projection is
// X[1024x64] . W[64x24] done with v_mfma_f32_16x16x32_f16 (16 waves x 4
// M-tiles x 2 N-tiles x 2 K-steps). A-frags load x straight from global
// (f32->f16), B-frags from weights. D (C-layout: row=quad*4+reg, col=lane&15)
// scattered to LDS planes; q routed through a qpl plane since the tap phase
// needs each thread's own pixel. Taps identical to round 12 (clamped +
// predicated, conflict-free b128 reads). LDS 64 KB.
__global__ __launch_bounds__(1024, 4) void fused_kernel(
    const float* __restrict__ x,      // [B][64][32][32]
    const float* __restrict__ wq,     // [64][64]
    const float* __restrict__ wk,
    const float* __restrict__ wv,
    const float* __restrict__ rel_h,  // [32][7]
    const float* __restrict__ rel_w,  // [32][7]
    const float* __restrict__ cv,     // [8]
    float* __restrict__ out)          // [B][64][32][32]
{
    __shared__ __attribute__((aligned(16))) f32x4 kplv[NPIX];  // k[0:8] f16   16KB
    __shared__ __attribute__((aligned(16))) f32x4 vpl0[NPIX];  // v[0:4] f32   16KB
    __shared__ __attribute__((aligned(16))) f32x4 vpl1[NPIX];  // v[4:8] f32   16KB
    __shared__ __attribute__((aligned(16))) f32x4 qplv[NPIX];  // q[0:8] f16   16KB

    const int bi  = blockIdx.x;
    const int xcd = bi & 7;            // XCD swizzle (image's 8 groups share L2)
    const int t   = bi >> 3;
    const int im  = t & 3;
    const int g   = t >> 2;
    const int b   = im * 8 + xcd;
    const int o0  = g * CPGc;
    const int tid = threadIdx.x;       // = pixel index 0..1023
    const int w   = tid & 31;
    const int h   = tid >> 5;

    const int lane = tid & 63;
    const int wp   = (tid >> 6) << 6;  // wave's 64-pixel base
    const int an   = lane & 15;        // A m-index / B,D n-index
    const int quad = lane >> 4;

    const float* xb = x + (size_t)b * CINc * NPIX;

    // ---------- B fragments (weights, f32 -> f16) ----------
    // N-tile0: n<8 -> k channel n, n>=8 -> v channel n-8.  N-tile1: q (n>=8 pad).
    h8 bf[2][2];
    {
        const float* br0 = (an < 8) ? (wk + (o0 + an) * CINc)
                                    : (wv + (o0 + an - 8) * CINc);
        const float* br1 = wq + (o0 + ((an < 8) ? an : 0)) * CINc;
#pragma unroll
        for (int ks = 0; ks < 2; ++ks) {
            const int c0 = ks * 32 + quad * 8;
#pragma unroll
            for (int jj = 0; jj < 8; ++jj) {
                bf[0][ks][jj] = (_Float16)br0[c0 + jj];
                bf[1][ks][jj] = (_Float16)br1[c0 + jj];
            }
        }
    }

    // ---------- MFMA projection: 4 M-tiles x 2 N-tiles, K=64 in 2 steps ----------
    f32x4 acc0[4], acc1[4];
#pragma unroll
    for (int m = 0; m < 4; ++m) { acc0[m] = (f32x4)0.f; acc1[m] = (f32x4)0.f; }

#pragma unroll
    for (int m = 0; m < 4; ++m) {
        const float* xpx = xb + wp + m * 16 + an;   // this lane's pixel column
#pragma unroll
        for (int ks = 0; ks < 2; ++ks) {
            const int c0 = ks * 32 + quad * 8;
            h8 a;
#pragma unroll
            for (int jj = 0; jj < 8; ++jj)
                a[jj] = (_Float16)xpx[(c0 + jj) * NPIX];
            acc0[m] = __builtin_amdgcn_mfma_f32_16x16x32_f16(a, bf[0][ks], acc0[m], 0, 0, 0);
            acc1[m] = __builtin_amdgcn_mfma_f32_16x16x32_f16(a, bf[1][ks], acc1[m], 0, 0, 0);
        }
    }

    // ---------- scatter D -> LDS planes (C-layout: pix = quad*4+reg) ----------
    {
        _Float16* kp16 = (_Float16*)kplv;
        _Float16* qp16 = (_Float16*)qplv;
        float*    v0f  = (float*)vpl0;
        float*    v1f  = (float*)vpl1;
#pragma unroll
        for (int m = 0; m < 4; ++m) {
#pragma unroll
            for (int r = 0; r < 4; ++r) {
                const int pix = wp + m * 16 + quad * 4 + r;
                const float d0 = acc0[m][r];
                if (an < 8) {
                    kp16[pix * 8 + an] = (_Float16)d0;
                    qp16[pix * 8 + an] = (_Float16)acc1[m][r];
                } else {
                    const int c = an - 8;
                    if (c < 4) v0f[pix * 4 + c]       = d0;
                    else       v1f[pix * 4 + (c - 4)] = d0;
                }
            }
        }
    }

    __syncthreads();

    // ---------- own-pixel q ----------
    f32x4 qraw = qplv[tid];
    const h2* qh = (const h2*)&qraw;
    h2 q2[4] = {qh[0], qh[1], qh[2], qh[3]};
    float qf[CPGc];
#pragma unroll
    for (int jj = 0; jj < 4; ++jj) {
        qf[2 * jj]     = (float)q2[jj].x;
        qf[2 * jj + 1] = (float)q2[jj].y;
    }

    // qrel[t] = sum_oi q[oi] * rel[oi][t]
    const bool use_h = (g < 4);
    const float* relp = use_h ? (rel_h + o0 * KSc) : (rel_w + (o0 - 32) * KSc);
    float qrel[KSc];
#pragma unroll
    for (int tt = 0; tt < KSc; ++tt) {
        float s = 0.f;
#pragma unroll
        for (int oi = 0; oi < CPGc; ++oi)
            s = fmaf(qf[oi], relp[oi * KSc + tt], s);
        qrel[tt] = s;
    }

    // per-kj clamped col + in-bounds mask
    int  xcl[KSc];
    bool xin[KSc];
#pragma unroll
    for (int kj = 0; kj < KSc; ++kj) {
        const int xx = w + kj - PADc;
        xin[kj] = (xx >= 0) && (xx < WWc);
        xcl[kj] = min(max(xx, 0), WWc - 1);
    }

    // ---------- taps: clamped reads + predication (round-12 proven) ----------
    float den = 0.f;
    float acc[CPGc];
#pragma unroll
    for (int oi = 0; oi < CPGc; ++oi) acc[oi] = 0.f;

#pragma unroll
    for (int ki = 0; ki < KSc; ++ki) {
        const int y    = h + ki - PADc;
        const bool yin = (y >= 0) && (y < HHc);
        const int base = min(max(y, 0), HHc - 1) * WWc;
#pragma unroll
        for (int kj = 0; kj < KSc; ++kj) {
            const int p = base + xcl[kj];
            const f32x4 kraw = kplv[p];
            const f32x4 v0   = vpl0[p];
            const f32x4 v1   = vpl1[p];
            const bool in = yin && xin[kj];

            float d = 0.f;
#if HAVE_FDOT2
            const h2* kh = (const h2*)&kraw;
            d = __builtin_amdgcn_fdot2(q2[0], kh[0], d, false);
            d = __builtin_amdgcn_fdot2(q2[1], kh[1], d, false);
            d = __builtin_amdgcn_fdot2(q2[2], kh[2], d, false);
            d = __builtin_amdgcn_fdot2(q2[3], kh[3], d, false);
#else
            const h2* kh = (const h2*)&kraw;
#pragma unroll
            for (int jj = 0; jj < 4; ++jj) {
                d = fmaf(qf[2 * jj],     (float)kh[jj].x, d);
                d = fmaf(qf[2 * jj + 1], (float)kh[jj].y, d);
            }
#endif
            const float s = (use_h ? qrel[ki] : qrel[kj]) + (in ? d : 0.f);
            const float e = __expf(s);      // OOB: e = exp(qrel) (ref zero-pad)
            den += e;
            const float ev = in ? e : 0.f;  // OOB taps contribute no v
            acc[0] = fmaf(ev, v0.x, acc[0]); acc[1] = fmaf(ev, v0.y, acc[1]);
            acc[2] = fmaf(ev, v0.z, acc[2]); acc[3] = fmaf(ev, v0.w, acc[3]);
            acc[4] = fmaf(ev, v1.x, acc[4]); acc[5] = fmaf(ev, v1.y, acc[5]);
            acc[6] = fmaf(ev, v1.z, acc[6]); acc[7] = fmaf(ev, v1.w, acc[7]);
        }
    }

    // ---------- adaptive mask + write ----------
    const int  r  = min(h, HHc - 1 - h);
    const int  lo = (h <= HHc - 1 - h) ? r : r + 1;
    const int  hi = HHc - 1 - r;
    const bool in_ring = (w >= lo) && (w <= hi);
    const float cvg = cv[g];
    float om = ((float)r - 15.0f + cvg * 16.0f) * (1.0f / 3.0f) + 1.0f;
    om = fminf(fmaxf(om, 0.0f), 1.0f);
    const float maskv = in_ring ? om : 1.0f;
    const float scale = maskv / den;

    float* ob = out + ((size_t)b * COc + o0) * NPIX + tid;
#pragma unroll
    for (int oi = 0; oi < CPGc; ++oi)
        ob[(size_t)oi * NPIX] = acc[oi] * scale;
}

extern "C" void kernel_launch(void* const* d_in, const int* in_sizes, int n_in,
                              void* d_out, int out_size, void* d_ws, size_t ws_size,
                              hipStream_t stream) {
    const float* x     = (const float*)d_in[0];
    const float* wq    = (const float*)d_in[1];
    const float* wk    = (const float*)d_in[2];
    const float* wv    = (const float*)d_in[3];
    const float* rel_h = (const float*)d_in[4];
    const float* rel_w = (const float*)d_in[5];
    const float* cv    = (const float*)d_in[6];
    float* out = (float*)d_out;

    fused_kernel<<<256, 1024, 0, stream>>>(x, wq, wk, wv, rel_h, rel_w, cv, out);
}

// Round 14
// 87.390 us; speedup vs baseline: 1.7302x; 1.0015x over previous
//
#include <hip/hip_runtime.h>

#define BB    32
#define CINc  64
#define HHc   32
#define WWc   32
#define COc   64
#define KSc   7
#define GGc   8
#define PADc  3
#define CPGc  8
#define NPIX  (HHc * WWc)      // 1024

typedef _Float16 h8    __attribute__((ext_vector_type(8)));
typedef _Float16 h2    __attribute__((ext_vector_type(2)));
typedef float    f32x4 __attribute__((ext_vector_type(4)));

#if defined(__has_builtin)
#if __has_builtin(__builtin_amdgcn_fdot2)
#define HAVE_FDOT2 1
#endif
#endif

// MFMA projection (round 13, verified) + f16 v-plane (round 14): per block
// (image, group), X[1024x64].W[64x24] via v_mfma_f32_16x16x32_f16. All three
// LDS planes now f16x8 = 16 B/position -> taps read 2 x ds_read_b128 instead
// of 3 (LDS pipe was the largest remaining term, ~12 us). v accumulation uses
// v_fma_mix_f32 (f16 operand, f32 acc) so no cvt instructions are added.
// e/den/acc stay f32 (e unnormalized, up to e^40). LDS 48 KB.
__global__ __launch_bounds__(1024, 4) void fused_kernel(
    const float* __restrict__ x,      // [B][64][32][32]
    const float* __restrict__ wq,     // [64][64]
    const float* __restrict__ wk,
    const float* __restrict__ wv,
    const float* __restrict__ rel_h,  // [32][7]
    const float* __restrict__ rel_w,  // [32][7]
    const float* __restrict__ cv,     // [8]
    float* __restrict__ out)          // [B][64][32][32]
{
    __shared__ __attribute__((aligned(16))) f32x4 kplv[NPIX];  // k[0:8] f16  16KB
    __shared__ __attribute__((aligned(16))) f32x4 vplv[NPIX];  // v[0:8] f16  16KB
    __shared__ __attribute__((aligned(16))) f32x4 qplv[NPIX];  // q[0:8] f16  16KB

    const int bi  = blockIdx.x;
    const int xcd = bi & 7;            // XCD swizzle (image's 8 groups share L2)
    const int t   = bi >> 3;
    const int im  = t & 3;
    const int g   = t >> 2;
    const int b   = im * 8 + xcd;
    const int o0  = g * CPGc;
    const int tid = threadIdx.x;       // = pixel index 0..1023
    const int w   = tid & 31;
    const int h   = tid >> 5;

    const int lane = tid & 63;
    const int wp   = (tid >> 6) << 6;  // wave's 64-pixel base
    const int an   = lane & 15;        // A m-index / B,D n-index
    const int quad = lane >> 4;

    const float* xb = x + (size_t)b * CINc * NPIX;

    // ---------- B fragments (weights, f32 -> f16) ----------
    // N-tile0: n<8 -> k channel n, n>=8 -> v channel n-8.  N-tile1: q (n>=8 pad).
    h8 bf[2][2];
    {
        const float* br0 = (an < 8) ? (wk + (o0 + an) * CINc)
                                    : (wv + (o0 + an - 8) * CINc);
        const float* br1 = wq + (o0 + ((an < 8) ? an : 0)) * CINc;
#pragma unroll
        for (int ks = 0; ks < 2; ++ks) {
            const int c0 = ks * 32 + quad * 8;
#pragma unroll
            for (int jj = 0; jj < 8; ++jj) {
                bf[0][ks][jj] = (_Float16)br0[c0 + jj];
                bf[1][ks][jj] = (_Float16)br1[c0 + jj];
            }
        }
    }

    // ---------- MFMA projection: 4 M-tiles x 2 N-tiles, K=64 in 2 steps ----------
    f32x4 acc0[4], acc1[4];
#pragma unroll
    for (int m = 0; m < 4; ++m) { acc0[m] = (f32x4)0.f; acc1[m] = (f32x4)0.f; }

#pragma unroll
    for (int m = 0; m < 4; ++m) {
        const float* xpx = xb + wp + m * 16 + an;   // this lane's pixel column
#pragma unroll
        for (int ks = 0; ks < 2; ++ks) {
            const int c0 = ks * 32 + quad * 8;
            h8 a;
#pragma unroll
            for (int jj = 0; jj < 8; ++jj)
                a[jj] = (_Float16)xpx[(c0 + jj) * NPIX];
            acc0[m] = __builtin_amdgcn_mfma_f32_16x16x32_f16(a, bf[0][ks], acc0[m], 0, 0, 0);
            acc1[m] = __builtin_amdgcn_mfma_f32_16x16x32_f16(a, bf[1][ks], acc1[m], 0, 0, 0);
        }
    }

    // ---------- scatter D -> LDS planes (C-layout: pix = quad*4+reg) ----------
    {
        _Float16* kp16 = (_Float16*)kplv;
        _Float16* qp16 = (_Float16*)qplv;
        _Float16* vp16 = (_Float16*)vplv;
#pragma unroll
        for (int m = 0; m < 4; ++m) {
#pragma unroll
            for (int r = 0; r < 4; ++r) {
                const int pix = wp + m * 16 + quad * 4 + r;
                const float d0 = acc0[m][r];
                if (an < 8) {
                    kp16[pix * 8 + an] = (_Float16)d0;
                    qp16[pix * 8 + an] = (_Float16)acc1[m][r];
                } else {
                    vp16[pix * 8 + (an - 8)] = (_Float16)d0;
                }
            }
        }
    }

    __syncthreads();

    // ---------- own-pixel q ----------
    f32x4 qraw = qplv[tid];
    const h2* qh = (const h2*)&qraw;
    h2 q2[4] = {qh[0], qh[1], qh[2], qh[3]};
    float qf[CPGc];
#pragma unroll
    for (int jj = 0; jj < 4; ++jj) {
        qf[2 * jj]     = (float)q2[jj].x;
        qf[2 * jj + 1] = (float)q2[jj].y;
    }

    // qrel[t] = sum_oi q[oi] * rel[oi][t]
    const bool use_h = (g < 4);
    const float* relp = use_h ? (rel_h + o0 * KSc) : (rel_w + (o0 - 32) * KSc);
    float qrel[KSc];
#pragma unroll
    for (int tt = 0; tt < KSc; ++tt) {
        float s = 0.f;
#pragma unroll
        for (int oi = 0; oi < CPGc; ++oi)
            s = fmaf(qf[oi], relp[oi * KSc + tt], s);
        qrel[tt] = s;
    }

    // per-kj clamped col + in-bounds mask
    int  xcl[KSc];
    bool xin[KSc];
#pragma unroll
    for (int kj = 0; kj < KSc; ++kj) {
        const int xx = w + kj - PADc;
        xin[kj] = (xx >= 0) && (xx < WWc);
        xcl[kj] = min(max(xx, 0), WWc - 1);
    }

    // ---------- taps: clamped reads + predication ----------
    float den = 0.f;
    float acc[CPGc];
#pragma unroll
    for (int oi = 0; oi < CPGc; ++oi) acc[oi] = 0.f;

#pragma unroll
    for (int ki = 0; ki < KSc; ++ki) {
        const int y    = h + ki - PADc;
        const bool yin = (y >= 0) && (y < HHc);
        const int base = min(max(y, 0), HHc - 1) * WWc;
#pragma unroll
        for (int kj = 0; kj < KSc; ++kj) {
            const int p = base + xcl[kj];
            const f32x4 kraw = kplv[p];
            const f32x4 vraw = vplv[p];
            const bool in = yin && xin[kj];

            float d = 0.f;
            const h2* kh = (const h2*)&kraw;
            const h2* vh = (const h2*)&vraw;
#if HAVE_FDOT2
            d = __builtin_amdgcn_fdot2(q2[0], kh[0], d, false);
            d = __builtin_amdgcn_fdot2(q2[1], kh[1], d, false);
            d = __builtin_amdgcn_fdot2(q2[2], kh[2], d, false);
            d = __builtin_amdgcn_fdot2(q2[3], kh[3], d, false);
#else
#pragma unroll
            for (int jj = 0; jj < 4; ++jj) {
                d = fmaf(qf[2 * jj],     (float)kh[jj].x, d);
                d = fmaf(qf[2 * jj + 1], (float)kh[jj].y, d);
            }
#endif
            const float s = (use_h ? qrel[ki] : qrel[kj]) + (in ? d : 0.f);
            const float e = __expf(s);      // OOB: e = exp(qrel) (ref zero-pad)
            den += e;
            const float ev = in ? e : 0.f;  // OOB taps contribute no v
            // v_fma_mix_f32: f16 v operand fused into f32 FMA (no cvt insts)
            acc[0] = fmaf(ev, (float)vh[0].x, acc[0]);
            acc[1] = fmaf(ev, (float)vh[0].y, acc[1]);
            acc[2] = fmaf(ev, (float)vh[1].x, acc[2]);
            acc[3] = fmaf(ev, (float)vh[1].y, acc[3]);
            acc[4] = fmaf(ev, (float)vh[2].x, acc[4]);
            acc[5] = fmaf(ev, (float)vh[2].y, acc[5]);
            acc[6] = fmaf(ev, (float)vh[3].x, acc[6]);
            acc[7] = fmaf(ev, (float)vh[3].y, acc[7]);
        }
    }

    // ---------- adaptive mask + write ----------
    const int  r  = min(h, HHc - 1 - h);
    const int  lo = (h <= HHc - 1 - h) ? r : r + 1;
    const int  hi = HHc - 1 - r;
    const bool in_ring = (w >= lo) && (w <= hi);
    const float cvg = cv[g];
    float om = ((float)r - 15.0f + cvg * 16.0f) * (1.0f / 3.0f) + 1.0f;
    om = fminf(fmaxf(om, 0.0f), 1.0f);
    const float maskv = in_ring ? om : 1.0f;
    const float scale = maskv / den;

    float* ob = out + ((size_t)b * COc + o0) * NPIX + tid;
#pragma unroll
    for (int oi = 0; oi < CPGc; ++oi)
        ob[(size_t)oi * NPIX] = acc[oi] * scale;
}

extern "C" void kernel_launch(void* const* d_in, const int* in_sizes, int n_in,
                              void* d_out, int out_size, void* d_ws, size_t ws_size,
                              hipStream_t stream) {
    const float* x     = (const float*)d_in[0];
    const float* wq    = (const float*)d_in[1];
    const float* wk    = (const float*)d_in[2];
    const float* wv    = (const float*)d_in[3];
    const float* rel_h = (const float*)d_in[4];
    const float* rel_w = (const float*)d_in[5];
    const float* cv    = (const float*)d_in[6];
    float* out = (float*)d_out;

    fused_kernel<<<256, 1024, 0, stream>>>(x, wq, wk, wv, rel_h, rel_w, cv, out);
}